// Round 1
// baseline (528.681 us; speedup 1.0000x reference)
//
#include <hip/hip_runtime.h>
#include <hip/hip_bf16.h>

#define N_NODES 100000
#define N_EDGES 1600000

#define SCAN_M (N_NODES + 1)
#define SCAN_NB ((SCAN_M + 1023) / 1024)   // 98

// ---------------- CSR build ----------------

__global__ __launch_bounds__(256) void k_hist(const int* __restrict__ row, int* __restrict__ cnt) {
    int e = blockIdx.x * 256 + threadIdx.x;
    if (e < N_EDGES) atomicAdd(&cnt[row[e] + 1], 1);
}

__global__ __launch_bounds__(256) void k_scan1(const int* __restrict__ a, int* __restrict__ bsum) {
    __shared__ int s[256];
    int t = threadIdx.x;
    int base = blockIdx.x * 1024 + t * 4;
    int v = 0;
    #pragma unroll
    for (int j = 0; j < 4; ++j) if (base + j < SCAN_M) v += a[base + j];
    s[t] = v; __syncthreads();
    for (int st = 128; st > 0; st >>= 1) { if (t < st) s[t] += s[t + st]; __syncthreads(); }
    if (t == 0) bsum[blockIdx.x] = s[0];
}

__global__ __launch_bounds__(256) void k_scan2(int* bsum) {
    __shared__ int s[256];
    int t = threadIdx.x;
    s[t] = (t < SCAN_NB) ? bsum[t] : 0;
    __syncthreads();
    for (int st = 1; st < 256; st <<= 1) {
        int v = (t >= st) ? s[t - st] : 0;
        __syncthreads();
        s[t] += v;
        __syncthreads();
    }
    if (t < SCAN_NB) bsum[t] = (t > 0) ? s[t - 1] : 0;   // exclusive
}

__global__ __launch_bounds__(256) void k_scan3(int* a, const int* __restrict__ bsum) {
    __shared__ int s[256];
    int t = threadIdx.x;
    int base = blockIdx.x * 1024 + t * 4;
    int v0 = (base + 0 < SCAN_M) ? a[base + 0] : 0;
    int v1 = (base + 1 < SCAN_M) ? a[base + 1] : 0;
    int v2 = (base + 2 < SCAN_M) ? a[base + 2] : 0;
    int v3 = (base + 3 < SCAN_M) ? a[base + 3] : 0;
    v1 += v0; v2 += v1; v3 += v2;
    s[t] = v3; __syncthreads();
    for (int st = 1; st < 256; st <<= 1) {
        int v = (t >= st) ? s[t - st] : 0;
        __syncthreads();
        s[t] += v;
        __syncthreads();
    }
    int pre = ((t > 0) ? s[t - 1] : 0) + bsum[blockIdx.x];
    if (base + 0 < SCAN_M) a[base + 0] = v0 + pre;
    if (base + 1 < SCAN_M) a[base + 1] = v1 + pre;
    if (base + 2 < SCAN_M) a[base + 2] = v2 + pre;
    if (base + 3 < SCAN_M) a[base + 3] = v3 + pre;
}

__global__ __launch_bounds__(256) void k_copyoff(const int* __restrict__ rp, int* __restrict__ off) {
    int n = blockIdx.x * 256 + threadIdx.x;
    if (n < N_NODES) off[n] = rp[n];
}

__global__ __launch_bounds__(256) void k_scatter(const int* __restrict__ row, const int* __restrict__ col,
                                                 const float* __restrict__ val, int* off,
                                                 int* __restrict__ cs, float* __restrict__ vs) {
    int e = blockIdx.x * 256 + threadIdx.x;
    if (e < N_EDGES) {
        int r = row[e];
        int p = atomicAdd(&off[r], 1);
        cs[p] = col[e];
        vs[p] = val[e];
    }
}

// ---------------- GEMM1: x[N,256] @ W1[256,32] -> out[N,32] ----------------
// block = 256 threads, 64 nodes/block, K staged in 4 chunks of 64.
__global__ __launch_bounds__(256) void k_gemm1(const float* __restrict__ x, const float* __restrict__ W,
                                               float* __restrict__ out) {
    __shared__ float xs[64][65];                 // 64 nodes x 64 k (padded)
    __shared__ __align__(16) float ws[64 * 32];  // k-chunk x 32 outs
    int tid = threadIdx.x;
    int bn = blockIdx.x * 64;
    int tn = tid & 31;        // node pair index: nodes 2*tn, 2*tn+1
    int to = tid >> 5;        // out group: outs 4*to .. 4*to+3
    float acc[2][4] = {};
    for (int kc = 0; kc < 4; ++kc) {
        int k0 = kc * 64;
        // stage x tile (coalesced float4 reads)
        #pragma unroll
        for (int i = 0; i < 4; ++i) {
            int idx = i * 256 + tid;
            int n = idx >> 4;
            int k4 = (idx & 15) * 4;
            float4 v = make_float4(0.f, 0.f, 0.f, 0.f);
            if (bn + n < N_NODES)
                v = *reinterpret_cast<const float4*>(&x[(size_t)(bn + n) * 256 + k0 + k4]);
            xs[n][k4 + 0] = v.x; xs[n][k4 + 1] = v.y; xs[n][k4 + 2] = v.z; xs[n][k4 + 3] = v.w;
        }
        // stage W chunk (flat 2048 floats)
        #pragma unroll
        for (int i = 0; i < 2; ++i) {
            int idx = i * 256 + tid;
            reinterpret_cast<float4*>(ws)[idx] =
                reinterpret_cast<const float4*>(W + k0 * 32)[idx];
        }
        __syncthreads();
        #pragma unroll 4
        for (int k = 0; k < 64; ++k) {
            float a0 = xs[2 * tn][k];
            float a1 = xs[2 * tn + 1][k];
            float4 w = *reinterpret_cast<const float4*>(&ws[k * 32 + 4 * to]);
            acc[0][0] += a0 * w.x; acc[0][1] += a0 * w.y; acc[0][2] += a0 * w.z; acc[0][3] += a0 * w.w;
            acc[1][0] += a1 * w.x; acc[1][1] += a1 * w.y; acc[1][2] += a1 * w.z; acc[1][3] += a1 * w.w;
        }
        __syncthreads();
    }
    #pragma unroll
    for (int i = 0; i < 2; ++i) {
        int n = bn + 2 * tn + i;
        if (n < N_NODES) {
            float4 r = make_float4(acc[i][0], acc[i][1], acc[i][2], acc[i][3]);
            *reinterpret_cast<float4*>(&out[(size_t)n * 32 + 4 * to]) = r;
        }
    }
}

// ---------------- SpMM (CSR): out[n,f] = sum_e val[e]*sup[col[e],f] ----------------
template<int F, bool BIASRELU>
__global__ __launch_bounds__(256) void k_spmm(const int* __restrict__ rp, const int* __restrict__ cs,
                                              const float* __restrict__ vs, const float* __restrict__ sup,
                                              const float* __restrict__ bias, float* __restrict__ out) {
    int gid = blockIdx.x * 256 + threadIdx.x;
    int n = gid / F;
    int f = gid - n * F;
    if (n >= N_NODES) return;
    int e0 = rp[n], e1 = rp[n + 1];
    float acc0 = 0.f, acc1 = 0.f;
    int e = e0;
    for (; e + 1 < e1; e += 2) {
        int c0 = cs[e], c1 = cs[e + 1];
        float v0 = vs[e], v1 = vs[e + 1];
        acc0 += v0 * sup[(size_t)c0 * F + f];
        acc1 += v1 * sup[(size_t)c1 * F + f];
    }
    if (e < e1) {
        int c = cs[e]; float v = vs[e];
        acc0 += v * sup[(size_t)c * F + f];
    }
    float acc = acc0 + acc1;
    if (BIASRELU) acc = fmaxf(acc + bias[f], 0.f);
    out[(size_t)n * F + f] = acc;
}

// ---------------- small GEMM with bias+relu: g[N,K] @ W[K,M] ----------------
template<int K, int M>
__global__ __launch_bounds__(256) void k_gemm_act(const float* __restrict__ g, const float* __restrict__ W,
                                                  const float* __restrict__ bias, float* __restrict__ out) {
    __shared__ float wsm[K * M];
    __shared__ float bs[M];
    for (int i = threadIdx.x; i < K * M; i += 256) wsm[i] = W[i];
    if (threadIdx.x < M) bs[threadIdx.x] = bias[threadIdx.x];
    __syncthreads();
    int gid = blockIdx.x * 256 + threadIdx.x;
    int n = gid / M;
    int f = gid - n * M;
    if (n >= N_NODES) return;
    const float* gr = g + (size_t)n * K;
    float acc = bs[f];
    #pragma unroll
    for (int k = 0; k < K; ++k) acc += gr[k] * wsm[k * M + f];
    out[(size_t)n * M + f] = fmaxf(acc, 0.f);
}

// ---------------- GEMM3 + global mean pool: g[N,48] @ W3[48,64] ----------------
__global__ __launch_bounds__(256) void k_gemm_pool(const float* __restrict__ g, const float* __restrict__ W,
                                                   const float* __restrict__ bias, float* __restrict__ pool) {
    __shared__ float wsm[48 * 64];
    __shared__ float red[256];
    for (int i = threadIdx.x; i < 48 * 64; i += 256) wsm[i] = W[i];
    __syncthreads();
    int f = threadIdx.x & 63;
    int nr = threadIdx.x >> 6;
    float b = bias[f];
    float psum = 0.f;
    int bn = blockIdx.x * 64;
    for (int c = 0; c < 16; ++c) {
        int n = bn + c * 4 + nr;
        if (n < N_NODES) {
            const float* gr = g + (size_t)n * 48;
            float acc = b;
            #pragma unroll
            for (int k = 0; k < 48; ++k) acc += gr[k] * wsm[k * 64 + f];
            psum += fmaxf(acc, 0.f);
        }
    }
    red[threadIdx.x] = psum;
    __syncthreads();
    if (threadIdx.x < 64) {
        float s = red[threadIdx.x] + red[threadIdx.x + 64] + red[threadIdx.x + 128] + red[threadIdx.x + 192];
        atomicAdd(&pool[threadIdx.x], s);
    }
}

// ---------------- head: mean -> FC1+relu -> FC2 -> softmax ----------------
__global__ void k_head(const float* __restrict__ pool, const float* __restrict__ fc1W,
                       const float* __restrict__ fc1b, const float* __restrict__ fc2W,
                       const float* __restrict__ fc2b, float* __restrict__ out) {
    __shared__ float z[32];
    __shared__ float lg[2];
    int t = threadIdx.x;
    const float inv = 1.0f / (float)N_NODES;
    if (t < 32) {
        float a = fc1b[t];
        for (int o = 0; o < 64; ++o) a += (pool[o] * inv) * fc1W[o * 32 + t];
        z[t] = fmaxf(a, 0.f);
    }
    __syncthreads();
    if (t < 2) {
        float l = fc2b[t];
        for (int j = 0; j < 32; ++j) l += z[j] * fc2W[j * 2 + t];
        lg[t] = l;
    }
    __syncthreads();
    if (t == 0) {
        float m = fmaxf(lg[0], lg[1]);
        float e0 = __expf(lg[0] - m), e1 = __expf(lg[1] - m);
        float s = e0 + e1;
        out[0] = e0 / s;
        out[1] = e1 / s;
    }
}

// ---------------- launch ----------------

extern "C" void kernel_launch(void* const* d_in, const int* in_sizes, int n_in,
                              void* d_out, int out_size, void* d_ws, size_t ws_size,
                              hipStream_t stream) {
    const float* x    = (const float*)d_in[0];
    const int*   row  = (const int*)d_in[1];
    const int*   col  = (const int*)d_in[2];
    const float* val  = (const float*)d_in[3];
    const float* W1   = (const float*)d_in[4];
    const float* b1   = (const float*)d_in[5];
    const float* W2   = (const float*)d_in[6];
    const float* b2   = (const float*)d_in[7];
    const float* W3   = (const float*)d_in[8];
    const float* b3   = (const float*)d_in[9];
    const float* fc1W = (const float*)d_in[10];
    const float* fc1b = (const float*)d_in[11];
    const float* fc2W = (const float*)d_in[12];
    const float* fc2b = (const float*)d_in[13];
    float* out = (float*)d_out;

    char* wsb = (char*)d_ws;
    size_t off = 0;
    auto alloc = [&](size_t bytes) {
        void* p = wsb + off;
        off += (bytes + 255) / 256 * 256;
        return p;
    };
    int*   row_ptr = (int*)alloc((size_t)(N_NODES + 1) * 4);
    int*   row_off = (int*)alloc((size_t)N_NODES * 4);
    int*   bsum    = (int*)alloc(1024 * 4);
    int*   cs      = (int*)alloc((size_t)N_EDGES * 4);
    float* vs      = (float*)alloc((size_t)N_EDGES * 4);
    float* bufA    = (float*)alloc((size_t)N_NODES * 64 * 4);
    float* bufB    = (float*)alloc((size_t)N_NODES * 64 * 4);
    float* pool    = (float*)alloc(64 * 4);

    hipMemsetAsync(row_ptr, 0, (size_t)(N_NODES + 1) * 4, stream);
    hipMemsetAsync(pool, 0, 64 * 4, stream);

    k_hist<<<(N_EDGES + 255) / 256, 256, 0, stream>>>(row, row_ptr);
    k_scan1<<<SCAN_NB, 256, 0, stream>>>(row_ptr, bsum);
    k_scan2<<<1, 256, 0, stream>>>(bsum);
    k_scan3<<<SCAN_NB, 256, 0, stream>>>(row_ptr, bsum);
    k_copyoff<<<(N_NODES + 255) / 256, 256, 0, stream>>>(row_ptr, row_off);
    k_scatter<<<(N_EDGES + 255) / 256, 256, 0, stream>>>(row, col, val, row_off, cs, vs);

    // layer 1: support = x@W1 ; h1 = relu(spmm(support)+b1)
    k_gemm1<<<(N_NODES + 63) / 64, 256, 0, stream>>>(x, W1, bufA);
    k_spmm<32, true><<<(N_NODES * 32) / 256, 256, 0, stream>>>(row_ptr, cs, vs, bufA, b1, bufB);
    // layer 2: g2 = spmm(h1) ; h2 = relu(g2@W2+b2)
    k_spmm<32, false><<<(N_NODES * 32) / 256, 256, 0, stream>>>(row_ptr, cs, vs, bufB, nullptr, bufA);
    k_gemm_act<32, 48><<<(N_NODES * 48) / 256, 256, 0, stream>>>(bufA, W2, b2, bufB);
    // layer 3: g3 = spmm(h2) ; pool += relu(g3@W3+b3)
    k_spmm<48, false><<<(N_NODES * 48) / 256, 256, 0, stream>>>(row_ptr, cs, vs, bufB, nullptr, bufA);
    k_gemm_pool<<<(N_NODES + 63) / 64, 256, 0, stream>>>(bufA, W3, b3, pool);
    // head
    k_head<<<1, 64, 0, stream>>>(pool, fc1W, fc1b, fc2W, fc2b, out);
}